// Round 4
// baseline (97.359 us; speedup 1.0000x reference)
//
#include <hip/hip_runtime.h>
#include <hip/hip_bf16.h>

typedef __attribute__((ext_vector_type(8))) short short8;
typedef __attribute__((ext_vector_type(4))) float f32x4;

#define MFMA16(a, b, c) __builtin_amdgcn_mfma_f32_16x16x32_bf16((a), (b), (c), 0, 0, 0)

__device__ __forceinline__ short f2bf(float f) {
  union { float f; unsigned u; } v; v.f = f;
  unsigned r = v.u + 0x7fffu + ((v.u >> 16) & 1u);   // RNE to bf16
  return (short)(r >> 16);
}
__device__ __forceinline__ unsigned pack2(float lo, float hi) {
  return (unsigned)(unsigned short)f2bf(lo) | ((unsigned)(unsigned short)f2bf(hi) << 16);
}

// ---------------------------------------------------------------------------
// K1: QKV projection.  Out[e][pix] = W[e][c] · x[c][pix] + b[e], bf16 outputs.
// (unchanged — ~30µs, near its ~26µs memory floor)
// ---------------------------------------------------------------------------
__global__ __launch_bounds__(256) void qkv_kernel(
    const float* __restrict__ x,
    const float* __restrict__ wq, const float* __restrict__ bq,
    const float* __restrict__ wk, const float* __restrict__ bk,
    const float* __restrict__ wv, const float* __restrict__ bv,
    short* __restrict__ Q, short* __restrict__ K, short* __restrict__ V)
{
  __shared__ alignas(16) short xs[64 * 256];     // [c][pix], linear, 32KB
  __shared__ alignas(16) short ws[3 * 64 * 64];  // [m][e][c ^ ((e&7)<<3)], 24KB
  __shared__ float bs[3 * 64];

  const int t    = threadIdx.x;
  const int b    = blockIdx.x >> 6;
  const int pt   = blockIdx.x & 63;
  const int pix0 = pt << 8;
  const float* xb = x + ((size_t)b << 20);

  #pragma unroll
  for (int i = 0; i < 16; ++i) {
    int f4 = i * 256 + t;
    int c  = f4 >> 6;
    int p4 = (f4 & 63) << 2;
    const float4 v = *reinterpret_cast<const float4*>(xb + c * 16384 + pix0 + p4);
    short* d = &xs[c * 256 + p4];
    d[0] = f2bf(v.x); d[1] = f2bf(v.y); d[2] = f2bf(v.z); d[3] = f2bf(v.w);
  }
  {
    #pragma unroll
    for (int i = 0; i < 16; ++i) {
      int idx = i * 256 + t;
      int e = idx >> 6, c = idx & 63;
      int d = e * 64 + (c ^ ((e & 7) << 3));
      ws[d]        = f2bf(wq[idx]);
      ws[d + 4096] = f2bf(wk[idx]);
      ws[d + 8192] = f2bf(wv[idx]);
    }
    if (t < 192) bs[t] = (t < 64) ? bq[t] : ((t < 128) ? bk[t - 64] : bv[t - 128]);
  }
  __syncthreads();

  const int lane = t & 63;
  const int wid  = t >> 6;
  const int p0   = wid << 6;
  const int l15  = lane & 15;
  const int lg   = lane >> 4;

  short8 bfrag[4][2];
  #pragma unroll
  for (int nt = 0; nt < 4; ++nt) {
    int pix = p0 + nt * 16 + l15;
    #pragma unroll
    for (int ks = 0; ks < 2; ++ks) {
      int cb = ks * 32 + (lg << 3);
      short8 f;
      #pragma unroll
      for (int j = 0; j < 8; ++j) f[j] = xs[(cb + j) * 256 + pix];
      bfrag[nt][ks] = f;
    }
  }

  #pragma unroll
  for (int m = 0; m < 3; ++m) {
    short* op = (m == 0) ? Q : ((m == 1) ? K : V);
    short8 afrag[4][2];
    #pragma unroll
    for (int mt = 0; mt < 4; ++mt) {
      int e = mt * 16 + l15;
      #pragma unroll
      for (int ks = 0; ks < 2; ++ks) {
        int cb8 = (ks * 4 + lg) ^ (e & 7);
        afrag[mt][ks] = *reinterpret_cast<const short8*>(&ws[m * 4096 + e * 64 + cb8 * 8]);
      }
    }
    #pragma unroll
    for (int mt = 0; mt < 4; ++mt) {
      #pragma unroll
      for (int nt = 0; nt < 4; ++nt) {
        f32x4 acc = {0.f, 0.f, 0.f, 0.f};
        acc = MFMA16(afrag[mt][0], bfrag[nt][0], acc);
        acc = MFMA16(afrag[mt][1], bfrag[nt][1], acc);
        int e_base = mt * 16 + (lg << 2);
        int pix = pix0 + p0 + nt * 16 + l15;
        #pragma unroll
        for (int r = 0; r < 4; ++r) {
          int e = e_base + r;
          float val = acc[r] + bs[m * 64 + e];
          op[(((size_t)b * 64 + e) << 14) + pix] = f2bf(val);
        }
      }
    }
  }
}

// ---------------------------------------------------------------------------
// K2: per-(b,e) attention.  512 thr = 8 waves, 16-row strip each.
// 64KB LDS (2 x 32KB) -> 2 blocks/CU.  Transposed tiles staged straight from
// global (coalesced row sweeps); T1/T2^T parked in packed-bf16 registers.
//   B1: Q -> KT -> T1 -> TV      B2: K -> QT -> VT -> T2^T
// All matmuls: identical NT swizzled ds_read_b128 pattern.
// ---------------------------------------------------------------------------
__global__ __launch_bounds__(512, 4) void attn_kernel(
    const short* __restrict__ Qg, const short* __restrict__ Kg,
    const short* __restrict__ Vg, float* __restrict__ out)
{
  __shared__ alignas(16) short B1[128 * 128];    // 32KB
  __shared__ alignas(16) short B2[128 * 128];    // 32KB

  const int t = threadIdx.x;
  const size_t base = (size_t)blockIdx.x << 14;  // (b*64+e)*16384

  // coalesced global rows -> swizzled LDS rows
  auto stage = [&](short* dst, const short* src) {
    #pragma unroll
    for (int i = 0; i < 4; ++i) {
      int eb  = i * 512 + t;                     // 16B block id
      int row = eb >> 4;
      int cb  = eb & 15;
      float4 v = *reinterpret_cast<const float4*>(src + (eb << 3));
      *reinterpret_cast<float4*>(dst + row * 128 + ((cb ^ (row & 7)) << 3)) = v;
    }
  };
  // transposed stage: dst[w][h] = src[h][w].  Reads: per-iteration 64 lanes
  // sweep 64 consecutive cols of one row = 128B coalesced (L3-hot).
  // Writes: swizzled b128 rows.
  auto stageT = [&](short* dst, const short* src) {
    const int w  = t & 127;
    const int rb = (t >> 7) << 5;                // 0,32,64,96
    const int w7 = w & 7;
    short v[32];
    #pragma unroll
    for (int k = 0; k < 32; ++k) v[k] = src[(rb + k) * 128 + w];
    #pragma unroll
    for (int k8 = 0; k8 < 4; ++k8) {
      int hb = (rb >> 3) + k8;
      *reinterpret_cast<short8*>(&dst[w * 128 + ((hb ^ w7) << 3)]) =
          *reinterpret_cast<const short8*>(&v[k8 * 8]);
    }
  };

  const int lane = t & 63;
  const int wid  = t >> 6;      // 0..7
  const int m0   = wid << 4;    // own 16-row strip
  const int l15  = lane & 15;
  const int lg   = lane >> 4;

  auto ldfrag = [&](const short* buf, int rowbase, int ks) -> short8 {
    int row = rowbase + l15;
    int cb  = (ks * 4 + lg) ^ (row & 7);
    return *reinterpret_cast<const short8*>(&buf[row * 128 + cb * 8]);
  };

  f32x4 acc[8];

  // acc = A(strip m0 of bufA) x B(bufB)^T over all 8 n-tiles
  auto matmul = [&](const short* bufA, const short* bufB) {
    short8 af[4];
    #pragma unroll
    for (int ks = 0; ks < 4; ++ks) af[ks] = ldfrag(bufA, m0, ks);
    #pragma unroll
    for (int n = 0; n < 8; ++n) {
      f32x4 a = {0.f, 0.f, 0.f, 0.f};
      #pragma unroll
      for (int ks = 0; ks < 4; ++ks) a = MFMA16(af[ks], ldfrag(bufB, n * 16, ks), a);
      acc[n] = a;
    }
  };

  // row softmax over acc (128 cols: 8 n-tiles x 16-lane groups), result
  // packed to bf16 pairs pk[r*4+np] = {n=2np, n=2np+1}
  auto softmax_pack = [&](unsigned* pk) {
    #pragma unroll
    for (int r = 0; r < 4; ++r) {
      float mx = acc[0][r];
      #pragma unroll
      for (int n = 1; n < 8; ++n) mx = fmaxf(mx, acc[n][r]);
      mx = fmaxf(mx, __shfl_xor(mx, 1));
      mx = fmaxf(mx, __shfl_xor(mx, 2));
      mx = fmaxf(mx, __shfl_xor(mx, 4));
      mx = fmaxf(mx, __shfl_xor(mx, 8));
      float p[8]; float s = 0.f;
      #pragma unroll
      for (int n = 0; n < 8; ++n) { p[n] = __expf((acc[n][r] - mx) * 0.125f); s += p[n]; }
      s += __shfl_xor(s, 1); s += __shfl_xor(s, 2);
      s += __shfl_xor(s, 4); s += __shfl_xor(s, 8);
      float inv = 1.0f / s;
      #pragma unroll
      for (int np = 0; np < 4; ++np)
        pk[r * 4 + np] = pack2(p[2 * np] * inv, p[2 * np + 1] * inv);
    }
  };

  // write packed strip to own 16 rows, swizzled
  auto store_pk = [&](short* dst, const unsigned* pk) {
    #pragma unroll
    for (int r = 0; r < 4; ++r) {
      int row = m0 + (lg << 2) + r;
      int sw  = (row & 7) << 3;
      #pragma unroll
      for (int np = 0; np < 4; ++np) {
        unsigned v = pk[r * 4 + np];
        int c0 = (2 * np) * 16 + l15;
        int c1 = c0 + 16;
        dst[row * 128 + (c0 ^ sw)] = (short)(v & 0xffff);
        dst[row * 128 + (c1 ^ sw)] = (short)(v >> 16);
      }
    }
  };

  unsigned t1[16], t2[16];

  // 1. Q, K
  stage(B1, Qg + base);
  stage(B2, Kg + base);
  __syncthreads();

  // 2. S1 = Q K^T -> softmax -> t1 regs
  matmul(B1, B2);
  softmax_pack(t1);
  __syncthreads();                               // S1 LDS reads done

  // 3. KT, QT staged from global (coalesced, L3-hot)
  stageT(B1, Kg + base);
  stageT(B2, Qg + base);
  __syncthreads();

  // 4. S2^T = K^T Q -> softmax -> t2 regs
  matmul(B1, B2);
  softmax_pack(t2);
  __syncthreads();                               // S2 LDS reads done

  // 5. T1 -> B1; VT -> B2
  store_pk(B1, t1);
  stageT(B2, Vg + base);
  __syncthreads();

  // 6. TV = T1 · V  (B-frags = rows of VT)
  matmul(B1, B2);
  __syncthreads();                               // TV reads of B1/B2 done

  // 7. TV -> B1 strips; T2^T -> B2 strips
  #pragma unroll
  for (int n = 0; n < 8; ++n) {
    #pragma unroll
    for (int r = 0; r < 4; ++r) {
      int row = m0 + (lg << 2) + r;
      int col = n * 16 + l15;
      B1[row * 128 + (col ^ ((row & 7) << 3))] = f2bf(acc[n][r]);
    }
  }
  store_pk(B2, t2);
  __syncthreads();

  // 8. OUT = TV · T2 (B-frags = rows of T2^T) -> fp32 global
  float* ob = out + base;
  #pragma unroll
  for (int n = 0; n < 8; ++n) {
    short8 af[4];
    f32x4 a = {0.f, 0.f, 0.f, 0.f};
    #pragma unroll
    for (int ks = 0; ks < 4; ++ks)
      a = MFMA16(ldfrag(B1, m0, ks), ldfrag(B2, n * 16, ks), a);
    (void)af;
    #pragma unroll
    for (int r = 0; r < 4; ++r) {
      int row = m0 + (lg << 2) + r;
      ob[row * 128 + n * 16 + l15] = a[r];
    }
  }
}

extern "C" void kernel_launch(void* const* d_in, const int* in_sizes, int n_in,
                              void* d_out, int out_size, void* d_ws, size_t ws_size,
                              hipStream_t stream) {
  const float* x  = (const float*)d_in[0];
  const float* wq = (const float*)d_in[1];
  const float* bq = (const float*)d_in[2];
  const float* wk = (const float*)d_in[3];
  const float* bk = (const float*)d_in[4];
  const float* wv = (const float*)d_in[5];
  const float* bv = (const float*)d_in[6];

  const size_t N = (size_t)16 * 64 * 128 * 128;
  short* Q = (short*)d_ws;
  short* K = Q + N;
  short* V = K + N;

  qkv_kernel<<<1024, 256, 0, stream>>>(x, wq, bq, wk, bk, wv, bv, Q, K, V);
  attn_kernel<<<1024, 512, 0, stream>>>(Q, K, V, (float*)d_out);
}